// Round 16
// baseline (5330.775 us; speedup 1.0000x reference)
//
#include <hip/hip_runtime.h>

#define NB 4096
#define ND 64
#define NH 256
#define NT 50
#define ROWS 16
#define THREADS 512
#define GRID (NB / ROWS)   // 256 blocks = exactly 1 per CU, single round

// Padded LDS layouts: 16-element groups at stride-20 floats (80 B) so the 4
// group-selecting lanes (q4) hit disjoint bank quads {0-3}{20-23}{8-11}{28-31}.
#define YIS 84            // yi row stride: (d>>4)*20 + (d&15)
#define ZS  324           // z row stride: (j>>4)*20 + (j&15)
#define RRS 68            // sRed row stride
#define RJS (ROWS * RRS)  // 1088: per-jhi slab (16 rows)

typedef float f2 __attribute__((ext_vector_type(2)));
typedef float f4 __attribute__((ext_vector_type(4)));

__device__ __forceinline__ float fast_tanh(float x) {
  // tanh(x) = 1 - 2/(exp(2x)+1); safe at +-inf
  float e = __expf(2.0f * x);
  return 1.0f - 2.0f * __builtin_amdgcn_rcpf(e + 1.0f);
}

// Fused single-instruction DPP butterfly add (r14: −128 instr/feval).
__device__ __forceinline__ float dpp_add_x1(float x) {
  float d;
  asm("v_add_f32_dpp %0, %1, %1 quad_perm:[1,0,3,2] row_mask:0xf bank_mask:0xf"
      : "=v"(d) : "v"(x));
  return d;
}
__device__ __forceinline__ float dpp_add_x2(float x) {
  float d;
  asm("v_add_f32_dpp %0, %1, %1 quad_perm:[2,3,0,1] row_mask:0xf bank_mask:0xf"
      : "=v"(d) : "v"(x));
  return d;
}
__device__ __forceinline__ float quad_reduce(float x) {
  return dpp_add_x2(dpp_add_x1(x));
}

// v_pk_fma_f32, op_sel broadcast of one src0 half, tied accumulator (r14).
// (r15 lesson: VOP3P cannot source AGPRs on gfx950 — "a" constraint fails.)
__device__ __forceinline__ void pk_fma_lo(f2 a, f2 b, f2& c) {
  asm("v_pk_fma_f32 %0, %1, %2, %0 op_sel:[0,0,0] op_sel_hi:[0,1,1]"
      : "+v"(c) : "v"(a), "v"(b));
}
__device__ __forceinline__ void pk_fma_hi(f2 a, f2 b, f2& c) {
  asm("v_pk_fma_f32 %0, %1, %2, %0 op_sel:[1,0,0] op_sel_hi:[1,1,1]"
      : "+v"(c) : "v"(a), "v"(b));
}

// Value barrier: redefines x as the output of an opaque asm op. The RA can
// no longer REMATERIALIZE it (remat needs a re-executable simple load as the
// def), so the value must stay resident in a VGPR for its whole live range.
__device__ __forceinline__ void pin(f2& x) { asm("" : "+v"(x)); }

// waves_per_eu(2,2): 256-VGPR budget so the ~190-reg pinned demand (128
// weight regs + accumulators/state) fits without scratch spill.
extern "C" __global__
__attribute__((amdgpu_flat_work_group_size(THREADS, THREADS)))
__attribute__((amdgpu_waves_per_eu(2, 2)))
void ode_kernel(const float* __restrict__ y0,
                const float* __restrict__ tt,
                const float* __restrict__ W1,
                const float* __restrict__ b1,
                const float* __restrict__ W2,
                const float* __restrict__ b2,
                float* __restrict__ out)
{
  __shared__ float sYI[ROWS * YIS];   // 1344 floats
  __shared__ float sZ [ROWS * ZS];    // 5184 floats
  __shared__ float sRed[4 * RJS];     // 4352 floats  (43.5 KB total)

  const int tid  = threadIdx.x;
  const int wv   = tid >> 6;        // wave 0..7
  const int lane = tid & 63;
  const int d    = lane;            // state dim
  const int row0 = (int)blockIdx.x * ROWS + wv;       // first owned row
  const int row1 = row0 + 8;                           // second owned row
  const int rh   = wv >> 2;         // row-group: G1/G2 work rows rh*8..rh*8+7
  const int q4   = lane & 3;        // G1 dgrp / G2 jlo (quad lane)
  const int jg   = (tid >> 2) & 63; // G1: j's 4jg..4jg+3
  const int jhi  = wv & 3;          // G2: j-supergroup
  const int dg2  = lane >> 2;       // G2: d's 4dg2..4dg2+3

  // ---- weights in registers, PINNED resident (no remat possible) ----
  f2 w1p[16][2];   // w1p[dd][jp] = { W1[q4*16+dd][4jg+2jp], ..+1 }
#pragma unroll
  for (int dd = 0; dd < 16; ++dd) {
    const f4 t = *(const f4*)&W1[(q4 * 16 + dd) * NH + 4 * jg];
    w1p[dd][0] = __builtin_shufflevector(t, t, 0, 1);
    w1p[dd][1] = __builtin_shufflevector(t, t, 2, 3);
    pin(w1p[dd][0]); pin(w1p[dd][1]);
  }
  const float4 b1v = *(const float4*)&b1[4 * jg];

  f2 w2p[16][2];   // w2p[jj][dp] = { W2[(jhi*4+q4)*16+jj][4dg2+2dp], ..+1 }
#pragma unroll
  for (int jj = 0; jj < 16; ++jj) {
    const f4 t = *(const f4*)&W2[((jhi * 4 + q4) * 16 + jj) * ND + 4 * dg2];
    w2p[jj][0] = __builtin_shufflevector(t, t, 0, 1);
    w2p[jj][1] = __builtin_shufflevector(t, t, 2, 3);
    pin(w2p[jj][0]); pin(w2p[jj][1]);
  }
  const float b2d = b2[d];

  // state: y[row0][d], y[row1][d]
  float ya = y0[row0 * ND + d];
  float yb = y0[row1 * ND + d];
  out[row0 * ND + d] = ya;
  out[row1 * ND + d] = yb;

  // precomputed LDS pointers
  const int yi_w0 = wv * YIS + (d >> 4) * 20 + (d & 15);
  const int yi_w1 = (wv + 8) * YIS + (d >> 4) * 20 + (d & 15);
  const float* yib = &sYI[(rh * 8) * YIS + q4 * 20];
  float*       zwb = &sZ[(rh * 8) * ZS + (jg >> 2) * 20 + 4 * (jg & 3)];
  const float* zrb = &sZ[(rh * 8) * ZS + (jhi * 4 + q4) * 20];
  float*       rwb = &sRed[jhi * RJS + (rh * 8) * RRS + 4 * dg2];
  const float* rob0 = &sRed[wv * RRS + d];
  const float* rob1 = &sRed[(wv + 8) * RRS + d];

  // f for both owned rows: writes yi, computes G1/G2 for the 8-row group,
  // returns this thread's two output slices.
  auto feval = [&](float yivA, float yivB, float& oA, float& oB) {
    sYI[yi_w0] = yivA;
    sYI[yi_w1] = yivB;
    __syncthreads();                     // Ba

    // ---- GEMM1: z[8 rows][2 j-pairs] partial over 16 dims (dgrp = q4) ----
    f2 z2[8][2];
#pragma unroll
    for (int r = 0; r < 8; ++r) { z2[r][0] = (f2)0.0f; z2[r][1] = (f2)0.0f; }
#pragma unroll
    for (int r = 0; r < 8; ++r) {
#pragma unroll
      for (int q = 0; q < 4; ++q) {
        const f4 a = *(const f4*)(yib + r * YIS + 4 * q);
        const f2 a01 = __builtin_shufflevector(a, a, 0, 1);
        const f2 a23 = __builtin_shufflevector(a, a, 2, 3);
#pragma unroll
        for (int jp = 0; jp < 2; ++jp) {
          pk_fma_lo(a01, w1p[4 * q + 0][jp], z2[r][jp]);
          pk_fma_hi(a01, w1p[4 * q + 1][jp], z2[r][jp]);
          pk_fma_lo(a23, w1p[4 * q + 2][jp], z2[r][jp]);
          pk_fma_hi(a23, w1p[4 * q + 3][jp], z2[r][jp]);
        }
      }
    }
    // quad reduce over dgrp (deterministic butterfly, fused DPP adds)
#pragma unroll
    for (int r = 0; r < 8; ++r) {
#pragma unroll
      for (int jp = 0; jp < 2; ++jp) {
        z2[r][jp].x = quad_reduce(z2[r][jp].x);
        z2[r][jp].y = quad_reduce(z2[r][jp].y);
      }
    }
    if (q4 == 0) {
#pragma unroll
      for (int r = 0; r < 8; ++r) {
        f4 zv;
        zv.x = fast_tanh(z2[r][0].x + b1v.x);
        zv.y = fast_tanh(z2[r][0].y + b1v.y);
        zv.z = fast_tanh(z2[r][1].x + b1v.z);
        zv.w = fast_tanh(z2[r][1].y + b1v.w);
        *(f4*)(zwb + r * ZS) = zv;
      }
    }
    __syncthreads();                     // Bb

    // ---- GEMM2: p[8 rows][2 d-pairs] partial over 16 j's (jgrp=jhi*4+q4) ----
    f2 p2[8][2];
#pragma unroll
    for (int r = 0; r < 8; ++r) { p2[r][0] = (f2)0.0f; p2[r][1] = (f2)0.0f; }
#pragma unroll
    for (int r = 0; r < 8; ++r) {
#pragma unroll
      for (int q = 0; q < 4; ++q) {
        const f4 a = *(const f4*)(zrb + r * ZS + 4 * q);
        const f2 a01 = __builtin_shufflevector(a, a, 0, 1);
        const f2 a23 = __builtin_shufflevector(a, a, 2, 3);
#pragma unroll
        for (int dp = 0; dp < 2; ++dp) {
          pk_fma_lo(a01, w2p[4 * q + 0][dp], p2[r][dp]);
          pk_fma_hi(a01, w2p[4 * q + 1][dp], p2[r][dp]);
          pk_fma_lo(a23, w2p[4 * q + 2][dp], p2[r][dp]);
          pk_fma_hi(a23, w2p[4 * q + 3][dp], p2[r][dp]);
        }
      }
    }
#pragma unroll
    for (int r = 0; r < 8; ++r) {
#pragma unroll
      for (int dp = 0; dp < 2; ++dp) {
        p2[r][dp].x = quad_reduce(p2[r][dp].x);
        p2[r][dp].y = quad_reduce(p2[r][dp].y);
      }
    }
    if (q4 == 0) {
#pragma unroll
      for (int r = 0; r < 8; ++r) {
        f4 pv;
        pv.x = p2[r][0].x; pv.y = p2[r][0].y;
        pv.z = p2[r][1].x; pv.w = p2[r][1].y;
        *(f4*)(rwb + r * RRS) = pv;
      }
    }
    __syncthreads();                     // Bc

    // owners: combine 4 j-supergroups for rows wv and wv+8, fixed order
    float a = b2d, b = b2d;
#pragma unroll
    for (int jh = 0; jh < 4; ++jh) a += rob0[jh * RJS];
#pragma unroll
    for (int jh = 0; jh < 4; ++jh) b += rob1[jh * RJS];
    oA = a; oB = b;
  };

  // Dormand-Prince 5(4) tableau (5th-order solution row)
  const float A10 = (float)(1.0 / 5.0);
  const float A20 = (float)(3.0 / 40.0),      A21 = (float)(9.0 / 40.0);
  const float A30 = (float)(44.0 / 45.0),     A31 = (float)(-56.0 / 15.0),
              A32 = (float)(32.0 / 9.0);
  const float A40 = (float)(19372.0 / 6561.0), A41 = (float)(-25360.0 / 2187.0),
              A42 = (float)(64448.0 / 6561.0), A43 = (float)(-212.0 / 729.0);
  const float A50 = (float)(9017.0 / 3168.0),  A51 = (float)(-355.0 / 33.0),
              A52 = (float)(46732.0 / 5247.0), A53 = (float)(49.0 / 176.0),
              A54 = (float)(-5103.0 / 18656.0);
  const float B0 = (float)(35.0 / 384.0),      B2 = (float)(500.0 / 1113.0),
              B3 = (float)(125.0 / 192.0),     B4 = (float)(-2187.0 / 6784.0),
              B5 = (float)(11.0 / 84.0);

  for (int ti = 0; ti < NT - 1; ++ti) {
    const float dt = (tt[ti + 1] - tt[ti]) * 0.25f;  // /SUBSTEPS, exact pow2
    for (int ss = 0; ss < 4; ++ss) {
      float k0a, k0b, k1a, k1b, k2a, k2b, k3a, k3b, k4a, k4b, k5a, k5b;
      feval(ya, yb, k0a, k0b);

      float yiA = fmaf(dt * A10, k0a, ya);
      float yiB = fmaf(dt * A10, k0b, yb);
      feval(yiA, yiB, k1a, k1b);

      yiA = ya; yiB = yb;
      yiA = fmaf(dt * A20, k0a, yiA); yiA = fmaf(dt * A21, k1a, yiA);
      yiB = fmaf(dt * A20, k0b, yiB); yiB = fmaf(dt * A21, k1b, yiB);
      feval(yiA, yiB, k2a, k2b);

      yiA = ya; yiB = yb;
      yiA = fmaf(dt * A30, k0a, yiA); yiA = fmaf(dt * A31, k1a, yiA);
      yiA = fmaf(dt * A32, k2a, yiA);
      yiB = fmaf(dt * A30, k0b, yiB); yiB = fmaf(dt * A31, k1b, yiB);
      yiB = fmaf(dt * A32, k2b, yiB);
      feval(yiA, yiB, k3a, k3b);

      yiA = ya; yiB = yb;
      yiA = fmaf(dt * A40, k0a, yiA); yiA = fmaf(dt * A41, k1a, yiA);
      yiA = fmaf(dt * A42, k2a, yiA); yiA = fmaf(dt * A43, k3a, yiA);
      yiB = fmaf(dt * A40, k0b, yiB); yiB = fmaf(dt * A41, k1b, yiB);
      yiB = fmaf(dt * A42, k2b, yiB); yiB = fmaf(dt * A43, k3b, yiB);
      feval(yiA, yiB, k4a, k4b);

      yiA = ya; yiB = yb;
      yiA = fmaf(dt * A50, k0a, yiA); yiA = fmaf(dt * A51, k1a, yiA);
      yiA = fmaf(dt * A52, k2a, yiA); yiA = fmaf(dt * A53, k3a, yiA);
      yiA = fmaf(dt * A54, k4a, yiA);
      yiB = fmaf(dt * A50, k0b, yiB); yiB = fmaf(dt * A51, k1b, yiB);
      yiB = fmaf(dt * A52, k2b, yiB); yiB = fmaf(dt * A53, k3b, yiB);
      yiB = fmaf(dt * A54, k4b, yiB);
      feval(yiA, yiB, k5a, k5b);

      // y_new = y + dt*(B0*k0 + B2*k2 + B3*k3 + B4*k4 + B5*k5)   (B1 = 0)
      ya = fmaf(dt * B0, k0a, ya);
      ya = fmaf(dt * B2, k2a, ya);
      ya = fmaf(dt * B3, k3a, ya);
      ya = fmaf(dt * B4, k4a, ya);
      ya = fmaf(dt * B5, k5a, ya);
      yb = fmaf(dt * B0, k0b, yb);
      yb = fmaf(dt * B2, k2b, yb);
      yb = fmaf(dt * B3, k3b, yb);
      yb = fmaf(dt * B4, k4b, yb);
      yb = fmaf(dt * B5, k5b, yb);
    }
    float* op = &out[(size_t)(ti + 1) * NB * ND];
    op[row0 * ND + d] = ya;
    op[row1 * ND + d] = yb;
  }
}

extern "C" void kernel_launch(void* const* d_in, const int* in_sizes, int n_in,
                              void* d_out, int out_size, void* d_ws, size_t ws_size,
                              hipStream_t stream) {
  const float* y0 = (const float*)d_in[0];
  const float* tt = (const float*)d_in[1];
  const float* W1 = (const float*)d_in[2];
  const float* b1 = (const float*)d_in[3];
  const float* W2 = (const float*)d_in[4];
  const float* b2 = (const float*)d_in[5];
  float* out = (float*)d_out;

  hipLaunchKernelGGL(ode_kernel, dim3(GRID), dim3(THREADS), 0, stream,
                     y0, tt, W1, b1, W2, b2, out);
}

// Round 17
// 5148.641 us; speedup vs baseline: 1.0354x; 1.0354x over previous
//
#include <hip/hip_runtime.h>

#define NB 4096
#define ND 64
#define NH 256
#define NT 50
#define ROWS 8
#define THREADS 512
#define GRID (NB / ROWS)   // 512 blocks -> 2 per CU if unified regs <= 128

// Padded LDS layouts: 16-element groups at stride-20 floats (80 B) so the 4
// group-selecting lanes (q4) hit disjoint bank quads.
#define YIS 84            // yi row stride
#define ZS  324           // z row stride (256 j: 16 groups x 20 + pad)
#define RRS 68            // sRed row stride
#define RJS (ROWS * RRS)  // 544: per-jhi slab

typedef float f2 __attribute__((ext_vector_type(2)));
typedef float f4 __attribute__((ext_vector_type(4)));

__device__ __forceinline__ float fast_tanh(float x) {
  // tanh(x) = 1 - 2/(exp(2x)+1); safe at +-inf
  float e = __expf(2.0f * x);
  return 1.0f - 2.0f * __builtin_amdgcn_rcpf(e + 1.0f);
}

// Fused single-instruction DPP butterfly add (r14).
__device__ __forceinline__ float dpp_add_x1(float x) {
  float d;
  asm("v_add_f32_dpp %0, %1, %1 quad_perm:[1,0,3,2] row_mask:0xf bank_mask:0xf"
      : "=v"(d) : "v"(x));
  return d;
}
__device__ __forceinline__ float dpp_add_x2(float x) {
  float d;
  asm("v_add_f32_dpp %0, %1, %1 quad_perm:[2,3,0,1] row_mask:0xf bank_mask:0xf"
      : "=v"(d) : "v"(x));
  return d;
}
__device__ __forceinline__ float quad_reduce(float x) {
  return dpp_add_x2(dpp_add_x1(x));
}

// v_pk_fma_f32, op_sel broadcast of one src0 half, tied accumulator (r14).
__device__ __forceinline__ void pk_fma_lo(f2 a, f2 b, f2& c) {
  asm("v_pk_fma_f32 %0, %1, %2, %0 op_sel:[0,0,0] op_sel_hi:[0,1,1]"
      : "+v"(c) : "v"(a), "v"(b));
}
__device__ __forceinline__ void pk_fma_hi(f2 a, f2 b, f2& c) {
  asm("v_pk_fma_f32 %0, %1, %2, %0 op_sel:[1,0,0] op_sel_hi:[1,1,1]"
      : "+v"(c) : "v"(a), "v"(b));
}

// r17 thesis (from r16's smoking gun): the compiler parks long-lived weight
// arrays in AGPRs; occupancy = 2048/(archVGPR+AGPR). All 128-weight variants
// = ~244 unified -> 8 waves/CU + a v_accvgpr_read tax on every weight use.
// This version holds only 64 weight regs/thread -> unified ~110-125 <= 128
// -> 16 waves/CU (4 waves/SIMD) AND a smaller (or zero) AGPR-read tax.
extern "C" __global__
__attribute__((amdgpu_flat_work_group_size(THREADS, THREADS)))
__attribute__((amdgpu_waves_per_eu(2, 4)))
void ode_kernel(const float* __restrict__ y0,
                const float* __restrict__ tt,
                const float* __restrict__ W1,
                const float* __restrict__ b1,
                const float* __restrict__ W2,
                const float* __restrict__ b2,
                float* __restrict__ out)
{
  __shared__ float sYI[ROWS * YIS];   // 672 floats
  __shared__ float sZ [ROWS * ZS];    // 2592 floats
  __shared__ float sRed[4 * RJS];     // 2176 floats  (21.8 KB total)

  const int tid  = threadIdx.x;
  const int wv   = tid >> 6;        // wave 0..7
  const int lane = tid & 63;
  const int d    = lane;            // state dim (owner role)
  const int row  = (int)blockIdx.x * ROWS + wv;   // state row (owner role)
  const int q4   = lane & 3;        // quad lane: G1 dim-quarter / G2 jc-low
  const int jp   = tid >> 2;        // G1: j-pair {2jp, 2jp+1}  (128 pairs)
  const int jc   = (wv & 3) * 4 + q4;               // G2: j-chunk (16 j each)
  const int dp   = (lane >> 2) | ((wv >> 2) << 4);  // G2: d-pair {2dp, 2dp+1}

  // ---- weights in registers: 32 + 32 = 64 regs/thread ----
  f2 w1p[16];   // w1p[dd] = { W1[q4*16+dd][2jp], W1[q4*16+dd][2jp+1] }
#pragma unroll
  for (int dd = 0; dd < 16; ++dd)
    w1p[dd] = *(const f2*)&W1[(q4 * 16 + dd) * NH + 2 * jp];
  const f2 b1p = *(const f2*)&b1[2 * jp];

  f2 w2p[16];   // w2p[jj] = { W2[jc*16+jj][2dp], W2[jc*16+jj][2dp+1] }
#pragma unroll
  for (int jj = 0; jj < 16; ++jj)
    w2p[jj] = *(const f2*)&W2[(jc * 16 + jj) * ND + 2 * dp];
  const float b2d = b2[d];

  // state: y[row][d], exactly one owner per element
  float y = y0[row * ND + d];
  out[row * ND + d] = y;

  // precomputed LDS offsets/pointers
  const int yi_woff = wv * YIS + (d >> 4) * 20 + (d & 15);
  const float* yib = &sYI[q4 * 20];                        // + r*YIS + 4q
  float*       zwb = &sZ[(jp >> 3) * 20 + ((2 * jp) & 15)]; // + r*ZS (f2)
  const float* zrb = &sZ[jc * 20];                         // + r*ZS + 4q
  float*       rwb = &sRed[(wv & 3) * RJS + 2 * dp];       // + r*RRS (f2)
  const float* rob = &sRed[wv * RRS + d];                  // + jh*RJS

  // f(yi) = tanh(yi @ W1 + b1) @ W2 + b2, scalar slice per owner thread.
  // Schedule: write yi | Ba | G1 (32 b128 bcast reads, 128 pk, quad-DPP,
  // pred tanh+f2 store) | Bb | G2 (same shape) | Bc | owner combines 4.
  auto feval = [&](float yiv) -> float {
    sYI[yi_woff] = yiv;
    __syncthreads();                     // Ba

    // ---- GEMM1: z{2 j}[8 rows] partial over 16 dims (quarter = q4) ----
    f2 z2[8];
#pragma unroll
    for (int r = 0; r < 8; ++r) z2[r] = (f2)0.0f;
#pragma unroll
    for (int r = 0; r < 8; ++r) {
#pragma unroll
      for (int q = 0; q < 4; ++q) {
        const f4 a = *(const f4*)(yib + r * YIS + 4 * q);
        const f2 a01 = __builtin_shufflevector(a, a, 0, 1);
        const f2 a23 = __builtin_shufflevector(a, a, 2, 3);
        pk_fma_lo(a01, w1p[4 * q + 0], z2[r]);
        pk_fma_hi(a01, w1p[4 * q + 1], z2[r]);
        pk_fma_lo(a23, w1p[4 * q + 2], z2[r]);
        pk_fma_hi(a23, w1p[4 * q + 3], z2[r]);
      }
    }
    // reduce the 4 dim-quarters across the quad (deterministic butterfly)
#pragma unroll
    for (int r = 0; r < 8; ++r) {
      z2[r].x = quad_reduce(z2[r].x);
      z2[r].y = quad_reduce(z2[r].y);
    }
    if (q4 == 0) {
#pragma unroll
      for (int r = 0; r < 8; ++r) {
        f2 zv;
        zv.x = fast_tanh(z2[r].x + b1p.x);
        zv.y = fast_tanh(z2[r].y + b1p.y);
        *(f2*)(zwb + r * ZS) = zv;
      }
    }
    __syncthreads();                     // Bb

    // ---- GEMM2: p{2 d}[8 rows] partial over 16 j's (chunk = jc) ----
    f2 p2[8];
#pragma unroll
    for (int r = 0; r < 8; ++r) p2[r] = (f2)0.0f;
#pragma unroll
    for (int r = 0; r < 8; ++r) {
#pragma unroll
      for (int q = 0; q < 4; ++q) {
        const f4 a = *(const f4*)(zrb + r * ZS + 4 * q);
        const f2 a01 = __builtin_shufflevector(a, a, 0, 1);
        const f2 a23 = __builtin_shufflevector(a, a, 2, 3);
        pk_fma_lo(a01, w2p[4 * q + 0], p2[r]);
        pk_fma_hi(a01, w2p[4 * q + 1], p2[r]);
        pk_fma_lo(a23, w2p[4 * q + 2], p2[r]);
        pk_fma_hi(a23, w2p[4 * q + 3], p2[r]);
      }
    }
#pragma unroll
    for (int r = 0; r < 8; ++r) {
      p2[r].x = quad_reduce(p2[r].x);
      p2[r].y = quad_reduce(p2[r].y);
    }
    if (q4 == 0) {
#pragma unroll
      for (int r = 0; r < 8; ++r)
        *(f2*)(rwb + r * RRS) = p2[r];
    }
    __syncthreads();                     // Bc

    // owner (wv, d): combine 4 j-supergroups, fixed order
    float o = b2d;
#pragma unroll
    for (int jh = 0; jh < 4; ++jh) o += rob[jh * RJS];
    return o;
  };

  // Dormand-Prince 5(4) tableau (5th-order solution row)
  const float A10 = (float)(1.0 / 5.0);
  const float A20 = (float)(3.0 / 40.0),      A21 = (float)(9.0 / 40.0);
  const float A30 = (float)(44.0 / 45.0),     A31 = (float)(-56.0 / 15.0),
              A32 = (float)(32.0 / 9.0);
  const float A40 = (float)(19372.0 / 6561.0), A41 = (float)(-25360.0 / 2187.0),
              A42 = (float)(64448.0 / 6561.0), A43 = (float)(-212.0 / 729.0);
  const float A50 = (float)(9017.0 / 3168.0),  A51 = (float)(-355.0 / 33.0),
              A52 = (float)(46732.0 / 5247.0), A53 = (float)(49.0 / 176.0),
              A54 = (float)(-5103.0 / 18656.0);
  const float B0 = (float)(35.0 / 384.0),      B2 = (float)(500.0 / 1113.0),
              B3 = (float)(125.0 / 192.0),     B4 = (float)(-2187.0 / 6784.0),
              B5 = (float)(11.0 / 84.0);

  for (int ti = 0; ti < NT - 1; ++ti) {
    const float dt = (tt[ti + 1] - tt[ti]) * 0.25f;  // /SUBSTEPS, exact pow2
    for (int ss = 0; ss < 4; ++ss) {
      const float k0 = feval(y);

      float yi = fmaf(dt * A10, k0, y);
      const float k1 = feval(yi);

      yi = y;
      yi = fmaf(dt * A20, k0, yi); yi = fmaf(dt * A21, k1, yi);
      const float k2 = feval(yi);

      yi = y;
      yi = fmaf(dt * A30, k0, yi); yi = fmaf(dt * A31, k1, yi);
      yi = fmaf(dt * A32, k2, yi);
      const float k3 = feval(yi);

      yi = y;
      yi = fmaf(dt * A40, k0, yi); yi = fmaf(dt * A41, k1, yi);
      yi = fmaf(dt * A42, k2, yi); yi = fmaf(dt * A43, k3, yi);
      const float k4 = feval(yi);

      yi = y;
      yi = fmaf(dt * A50, k0, yi); yi = fmaf(dt * A51, k1, yi);
      yi = fmaf(dt * A52, k2, yi); yi = fmaf(dt * A53, k3, yi);
      yi = fmaf(dt * A54, k4, yi);
      const float k5 = feval(yi);

      // y_new = y + dt*(B0*k0 + B2*k2 + B3*k3 + B4*k4 + B5*k5)   (B1 = 0)
      y = fmaf(dt * B0, k0, y);
      y = fmaf(dt * B2, k2, y);
      y = fmaf(dt * B3, k3, y);
      y = fmaf(dt * B4, k4, y);
      y = fmaf(dt * B5, k5, y);
    }
    out[(size_t)(ti + 1) * NB * ND + row * ND + d] = y;
  }
}

extern "C" void kernel_launch(void* const* d_in, const int* in_sizes, int n_in,
                              void* d_out, int out_size, void* d_ws, size_t ws_size,
                              hipStream_t stream) {
  const float* y0 = (const float*)d_in[0];
  const float* tt = (const float*)d_in[1];
  const float* W1 = (const float*)d_in[2];
  const float* b1 = (const float*)d_in[3];
  const float* W2 = (const float*)d_in[4];
  const float* b2 = (const float*)d_in[5];
  float* out = (float*)d_out;

  hipLaunchKernelGGL(ode_kernel, dim3(GRID), dim3(THREADS), 0, stream,
                     y0, tt, W1, b1, W2, b2, out);
}